// Round 1
// baseline (1481.250 us; speedup 1.0000x reference)
//
#include <hip/hip_runtime.h>
#include <hip/hip_bf16.h>
#include <stdint.h>

#define N_NODES 50000
#define N_EDGES 800000
#define D 128          // D_IN == D_OUT
#define K_DIM 256

typedef __attribute__((ext_vector_type(8))) short bf16x8;
typedef __attribute__((ext_vector_type(4))) float f32x4;

// ---- workspace layout ----
// sums : N_NODES * 128 f32   @ 0          (25,600,000 B)
// cnt  : N_NODES f32         @ CNT_OFF    (   200,000 B)
// wsw  : swizzled bf16 W     @ WSW_OFF    (    65,536 B)
#define CNT_OFF  (N_NODES * D * 4)
#define WSW_OFF  (CNT_OFF + N_NODES * 4)
#define ZERO_BYTES WSW_OFF

__device__ inline short f2bf(float x) {
  union { float f; uint32_t u; } v; v.f = x;
  uint32_t r = v.u + 0x7FFFu + ((v.u >> 16) & 1u);   // RNE
  return (short)(r >> 16);
}

// Pre-swizzle W (256x128 f32, row-major [k][n]) into per-lane contiguous bf16
// B-fragments for mfma_f32_16x16x32_bf16:
//   frag(kstep, ntile, lane) = W[kstep*32 + (lane>>4)*8 + j][ntile*16 + (lane&15)], j=0..7
__global__ __launch_bounds__(256) void k_wswz(const float* __restrict__ W,
                                              short* __restrict__ wsw) {
  int t = blockIdx.x * 256 + threadIdx.x;   // 0..4095  (8 kstep * 8 ntile * 64 lane)
  int kstep = t >> 9;
  int ntile = (t >> 6) & 7;
  int lane  = t & 63;
  int k0  = kstep * 32 + (lane >> 4) * 8;
  int col = ntile * 16 + (lane & 15);
  bf16x8 o;
  #pragma unroll
  for (int j = 0; j < 8; ++j) o[j] = f2bf(W[(k0 + j) * D + col]);
  *(bf16x8*)(wsw + t * 8) = o;
}

// Edge scatter: 32 threads per edge, float4 per thread.
__global__ __launch_bounds__(256) void k_edge(const float* __restrict__ feat,
                                              const int* __restrict__ idx,
                                              const float* __restrict__ w,
                                              float* __restrict__ sums,
                                              float* __restrict__ cnt) {
  int t = blockIdx.x * 256 + threadIdx.x;
  int e = t >> 5;
  int c = t & 31;
  int dst = idx[e];
  int src = idx[N_EDGES + e];
  float wt = w[e];
  f32x4 f = *(const f32x4*)(feat + (size_t)src * D + c * 4);
  float* s = sums + (size_t)dst * D + c * 4;
  atomicAdd(s + 0, f.x * wt);
  atomicAdd(s + 1, f.y * wt);
  atomicAdd(s + 2, f.z * wt);
  atomicAdd(s + 3, f.w * wt);
  if (c == 0) atomicAdd(cnt + dst, 1.0f);
}

// Fused mean + GEMM: out[n,:] = bf16(feat[n,:]) @ W0 + bf16(sums[n,:]*inv_c) @ W1 + b
// One wave per 16 rows; 8 n-tiles of 16 cols; K = 256 in 8 steps of 32. No LDS.
__global__ __launch_bounds__(256) void k_gemm(const float* __restrict__ feat,
                                              const float* __restrict__ sums,
                                              const float* __restrict__ cnt,
                                              const short* __restrict__ wsw,
                                              const float* __restrict__ bias,
                                              float* __restrict__ out) {
  int wave = threadIdx.x >> 6;
  int lane = threadIdx.x & 63;
  int waveId = blockIdx.x * 4 + wave;
  int R = waveId * 16;
  if (R >= N_NODES) return;

  int row_l = lane & 15;          // A row within tile / C col within tile
  int kq    = lane >> 4;          // 0..3
  int myrow = R + row_l;

  float c = cnt[myrow];
  float invc = 1.0f / fmaxf(c, 1.0f);

  f32x4 acc[8];
  #pragma unroll
  for (int nt = 0; nt < 8; ++nt) acc[nt] = (f32x4){0.f, 0.f, 0.f, 0.f};

  #pragma unroll
  for (int kstep = 0; kstep < 8; ++kstep) {
    int kbase = kstep * 32 + kq * 8;
    const float* srcrow;
    float scale;
    if (kstep < 4) { srcrow = feat + (size_t)myrow * D + kbase;         scale = 1.0f; }
    else           { srcrow = sums + (size_t)myrow * D + (kbase - D);   scale = invc; }
    f32x4 a0 = *(const f32x4*)(srcrow);
    f32x4 a1 = *(const f32x4*)(srcrow + 4);
    bf16x8 af;
    af[0] = f2bf(a0.x * scale); af[1] = f2bf(a0.y * scale);
    af[2] = f2bf(a0.z * scale); af[3] = f2bf(a0.w * scale);
    af[4] = f2bf(a1.x * scale); af[5] = f2bf(a1.y * scale);
    af[6] = f2bf(a1.z * scale); af[7] = f2bf(a1.w * scale);
    const bf16x8* wrow = (const bf16x8*)(wsw + ((size_t)kstep * 8 * 64 + lane) * 8);
    #pragma unroll
    for (int nt = 0; nt < 8; ++nt) {
      bf16x8 bf = wrow[nt * 64];
      acc[nt] = __builtin_amdgcn_mfma_f32_16x16x32_bf16(af, bf, acc[nt], 0, 0, 0);
    }
  }

  // C/D layout: col = lane&15, row = (lane>>4)*4 + reg   [m89-verified]
  #pragma unroll
  for (int nt = 0; nt < 8; ++nt) {
    int col = nt * 16 + row_l;
    float bv = bias[col];
    #pragma unroll
    for (int r = 0; r < 4; ++r) {
      int orow = R + kq * 4 + r;
      out[(size_t)orow * D + col] = acc[nt][r] + bv;
    }
  }
}

extern "C" void kernel_launch(void* const* d_in, const int* in_sizes, int n_in,
                              void* d_out, int out_size, void* d_ws, size_t ws_size,
                              hipStream_t stream) {
  const float* feature = (const float*)d_in[0];
  const int*   rel_idx = (const int*)d_in[1];
  const float* rel_w   = (const float*)d_in[2];
  const float* W       = (const float*)d_in[3];
  const float* b       = (const float*)d_in[4];
  float* out = (float*)d_out;

  char* ws = (char*)d_ws;
  float* sums = (float*)(ws);
  float* cnt  = (float*)(ws + CNT_OFF);
  short* wsw  = (short*)(ws + WSW_OFF);

  hipMemsetAsync(ws, 0, ZERO_BYTES, stream);
  k_wswz<<<16, 256, 0, stream>>>(W, wsw);
  k_edge<<<(N_EDGES * 32) / 256, 256, 0, stream>>>(feature, rel_idx, rel_w, sums, cnt);
  int gemmBlocks = (N_NODES / 16 + 3) / 4;   // 3125 waves -> 782 blocks of 4 waves
  k_gemm<<<gemmBlocks, 256, 0, stream>>>(feature, sums, cnt, wsw, b, out);
}

// Round 2
// 394.475 us; speedup vs baseline: 3.7550x; 3.7550x over previous
//
#include <hip/hip_runtime.h>
#include <hip/hip_bf16.h>
#include <stdint.h>

#define N_NODES 50000
#define N_EDGES 800000
#define D 128          // D_IN == D_OUT
#define K_DIM 256

typedef __attribute__((ext_vector_type(8))) short bf16x8;
typedef __attribute__((ext_vector_type(4))) float f32x4;

// ---- workspace layout (bytes) ----
#define SUMS_OFF  0                       // N_NODES*128 f32 = 25,600,000
#define WSW_OFF   25600000                // swizzled bf16 W  =     65,536
#define HIST_OFF  25665536                // N_NODES i32      =    200,000  (memset 0)
#define OFFS_OFF  25865536                // (N_NODES+1) i32  =    200,016 (padded)
#define CURS_OFF  26065552                // N_NODES i32      =    200,000
#define ESRC_OFF  26265552                // N_EDGES i32      =  3,200,000
#define EW_OFF    29465552                // N_EDGES f32      =  3,200,000
// total ~32.67 MB

__device__ inline short f2bf(float x) {
  union { float f; uint32_t u; } v; v.f = x;
  uint32_t r = v.u + 0x7FFFu + ((v.u >> 16) & 1u);   // RNE
  return (short)(r >> 16);
}

// Pre-swizzle W (256x128 f32, row-major [k][n]) into per-lane contiguous bf16
// B-fragments for mfma_f32_16x16x32_bf16.
__global__ __launch_bounds__(256) void k_wswz(const float* __restrict__ W,
                                              short* __restrict__ wsw) {
  int t = blockIdx.x * 256 + threadIdx.x;   // 0..4095
  int kstep = t >> 9;
  int ntile = (t >> 6) & 7;
  int lane  = t & 63;
  int k0  = kstep * 32 + (lane >> 4) * 8;
  int col = ntile * 16 + (lane & 15);
  bf16x8 o;
  #pragma unroll
  for (int j = 0; j < 8; ++j) o[j] = f2bf(W[(k0 + j) * D + col]);
  *(bf16x8*)(wsw + t * 8) = o;
}

// 1) histogram of dst degrees
__global__ __launch_bounds__(256) void k_hist(const int* __restrict__ idx,
                                              int* __restrict__ hist) {
  int e = blockIdx.x * 256 + threadIdx.x;
  if (e < N_EDGES) atomicAdd(&hist[idx[e]], 1);
}

// 2) exclusive prefix sum (single block, 256 threads, 196 elems/thread)
__global__ __launch_bounds__(256) void k_scan(const int* __restrict__ hist,
                                              int* __restrict__ offs,
                                              int* __restrict__ cursor) {
  __shared__ int part[256];
  const int CH = 196;                       // 256*196 = 50176 >= 50000
  int t = threadIdx.x;
  int base = t * CH;
  int s = 0;
  for (int i = 0; i < CH; ++i) {
    int ix = base + i;
    if (ix < N_NODES) s += hist[ix];
  }
  part[t] = s;
  __syncthreads();
  if (t == 0) {
    int run = 0;
    for (int i = 0; i < 256; ++i) { int v = part[i]; part[i] = run; run += v; }
    offs[N_NODES] = run;                    // == N_EDGES
  }
  __syncthreads();
  int run = part[t];
  for (int i = 0; i < CH; ++i) {
    int ix = base + i;
    if (ix < N_NODES) {
      offs[ix] = run; cursor[ix] = run;
      run += hist[ix];
    }
  }
}

// 3) scatter edges into CSR buckets
__global__ __launch_bounds__(256) void k_scatter(const int* __restrict__ idx,
                                                 const float* __restrict__ w,
                                                 int* __restrict__ cursor,
                                                 int* __restrict__ esrc,
                                                 float* __restrict__ ew) {
  int e = blockIdx.x * 256 + threadIdx.x;
  if (e < N_EDGES) {
    int dst = idx[e];
    int p = atomicAdd(&cursor[dst], 1);
    esrc[p] = idx[N_EDGES + e];
    ew[p]   = w[e];
  }
}

// 4) per-node ordered aggregation: 32 lanes per node, float4 per lane, no atomics
__global__ __launch_bounds__(256) void k_agg(const float* __restrict__ feat,
                                             const int* __restrict__ offs,
                                             const int* __restrict__ esrc,
                                             const float* __restrict__ ew,
                                             float* __restrict__ sums) {
  int t = blockIdx.x * 256 + threadIdx.x;
  int node = t >> 5;
  int c = t & 31;
  if (node >= N_NODES) return;
  int beg = offs[node], end = offs[node + 1];
  f32x4 acc = (f32x4){0.f, 0.f, 0.f, 0.f};
  for (int j = beg; j < end; ++j) {
    int   src = esrc[j];
    float wt  = ew[j];
    f32x4 f = *(const f32x4*)(feat + (size_t)src * D + c * 4);
    acc.x += f.x * wt; acc.y += f.y * wt; acc.z += f.z * wt; acc.w += f.w * wt;
  }
  *(f32x4*)(sums + (size_t)node * D + c * 4) = acc;
}

// 5) fused mean + GEMM: out = bf16(feat)@W0 + bf16(sums*invc)@W1 + b.  No LDS.
__global__ __launch_bounds__(256) void k_gemm(const float* __restrict__ feat,
                                              const float* __restrict__ sums,
                                              const int* __restrict__ offs,
                                              const short* __restrict__ wsw,
                                              const float* __restrict__ bias,
                                              float* __restrict__ out) {
  int wave = threadIdx.x >> 6;
  int lane = threadIdx.x & 63;
  int waveId = blockIdx.x * 4 + wave;
  int R = waveId * 16;
  if (R >= N_NODES) return;

  int row_l = lane & 15;
  int kq    = lane >> 4;
  int myrow = R + row_l;

  int deg = offs[myrow + 1] - offs[myrow];
  float invc = 1.0f / fmaxf((float)deg, 1.0f);

  f32x4 acc[8];
  #pragma unroll
  for (int nt = 0; nt < 8; ++nt) acc[nt] = (f32x4){0.f, 0.f, 0.f, 0.f};

  #pragma unroll
  for (int kstep = 0; kstep < 8; ++kstep) {
    int kbase = kstep * 32 + kq * 8;
    const float* srcrow;
    float scale;
    if (kstep < 4) { srcrow = feat + (size_t)myrow * D + kbase;        scale = 1.0f; }
    else           { srcrow = sums + (size_t)myrow * D + (kbase - D);  scale = invc; }
    f32x4 a0 = *(const f32x4*)(srcrow);
    f32x4 a1 = *(const f32x4*)(srcrow + 4);
    bf16x8 af;
    af[0] = f2bf(a0.x * scale); af[1] = f2bf(a0.y * scale);
    af[2] = f2bf(a0.z * scale); af[3] = f2bf(a0.w * scale);
    af[4] = f2bf(a1.x * scale); af[5] = f2bf(a1.y * scale);
    af[6] = f2bf(a1.z * scale); af[7] = f2bf(a1.w * scale);
    const bf16x8* wrow = (const bf16x8*)(wsw + ((size_t)kstep * 8 * 64 + lane) * 8);
    #pragma unroll
    for (int nt = 0; nt < 8; ++nt) {
      bf16x8 bf = wrow[nt * 64];
      acc[nt] = __builtin_amdgcn_mfma_f32_16x16x32_bf16(af, bf, acc[nt], 0, 0, 0);
    }
  }

  // C/D layout: col = lane&15, row = (lane>>4)*4 + reg
  #pragma unroll
  for (int nt = 0; nt < 8; ++nt) {
    int col = nt * 16 + row_l;
    float bv = bias[col];
    #pragma unroll
    for (int r = 0; r < 4; ++r) {
      int orow = R + kq * 4 + r;
      out[(size_t)orow * D + col] = acc[nt][r] + bv;
    }
  }
}

extern "C" void kernel_launch(void* const* d_in, const int* in_sizes, int n_in,
                              void* d_out, int out_size, void* d_ws, size_t ws_size,
                              hipStream_t stream) {
  const float* feature = (const float*)d_in[0];
  const int*   rel_idx = (const int*)d_in[1];
  const float* rel_w   = (const float*)d_in[2];
  const float* W       = (const float*)d_in[3];
  const float* b       = (const float*)d_in[4];
  float* out = (float*)d_out;

  char* ws = (char*)d_ws;
  float* sums  = (float*)(ws + SUMS_OFF);
  short* wsw   = (short*)(ws + WSW_OFF);
  int*   hist  = (int*)(ws + HIST_OFF);
  int*   offs  = (int*)(ws + OFFS_OFF);
  int*   curs  = (int*)(ws + CURS_OFF);
  int*   esrc  = (int*)(ws + ESRC_OFF);
  float* ew    = (float*)(ws + EW_OFF);

  hipMemsetAsync(hist, 0, N_NODES * sizeof(int), stream);
  k_wswz<<<16, 256, 0, stream>>>(W, wsw);
  k_hist<<<(N_EDGES + 255) / 256, 256, 0, stream>>>(rel_idx, hist);
  k_scan<<<1, 256, 0, stream>>>(hist, offs, curs);
  k_scatter<<<(N_EDGES + 255) / 256, 256, 0, stream>>>(rel_idx, rel_w, curs, esrc, ew);
  k_agg<<<(N_NODES * 32 + 255) / 256, 256, 0, stream>>>(feature, offs, esrc, ew, sums);
  int gemmBlocks = (N_NODES / 16 + 3) / 4;
  k_gemm<<<gemmBlocks, 256, 0, stream>>>(feature, sums, offs, wsw, b, out);
}

// Round 3
// 257.252 us; speedup vs baseline: 5.7580x; 1.5334x over previous
//
#include <hip/hip_runtime.h>
#include <hip/hip_bf16.h>
#include <stdint.h>

#define N_NODES 50000
#define N_EDGES 800000
#define D 128          // D_IN == D_OUT
#define K_DIM 256
#define NB_SCAN 196    // ceil(50000/256)

typedef __attribute__((ext_vector_type(8))) short bf16x8;
typedef __attribute__((ext_vector_type(4))) float f32x4;

// ---- workspace layout (bytes) ----
#define SUMS_OFF  0                       // N_NODES*128 f32 = 25,600,000
#define WSW_OFF   25600000                // swizzled bf16 W  =     65,536
#define HIST_OFF  25665536                // N_NODES i32      =    200,000  (memset 0)
#define OFFS_OFF  25865536                // (N_NODES+1) i32  =    200,016 (padded)
#define CURS_OFF  26065552                // N_NODES i32      =    200,000
#define EDGE_OFF  26265552                // N_EDGES int2 (src, w-bits) = 6,400,000
#define BSUM_OFF  32665552                // NB_SCAN i32 (pad 1024)
#define BOFF_OFF  32666576                // NB_SCAN i32 (pad 1024)
// total ~32.67 MB

__device__ inline short f2bf(float x) {
  union { float f; uint32_t u; } v; v.f = x;
  uint32_t r = v.u + 0x7FFFu + ((v.u >> 16) & 1u);   // RNE
  return (short)(r >> 16);
}

// Pre-swizzle W (256x128 f32 row-major) into per-lane bf16 B-fragments.
__global__ __launch_bounds__(256) void k_wswz(const float* __restrict__ W,
                                              short* __restrict__ wsw) {
  int t = blockIdx.x * 256 + threadIdx.x;   // 0..4095
  int kstep = t >> 9;
  int ntile = (t >> 6) & 7;
  int lane  = t & 63;
  int k0  = kstep * 32 + (lane >> 4) * 8;
  int col = ntile * 16 + (lane & 15);
  bf16x8 o;
  #pragma unroll
  for (int j = 0; j < 8; ++j) o[j] = f2bf(W[(k0 + j) * D + col]);
  *(bf16x8*)(wsw + t * 8) = o;
}

// 1) histogram of dst degrees
__global__ __launch_bounds__(256) void k_hist(const int* __restrict__ idx,
                                              int* __restrict__ hist) {
  int e = blockIdx.x * 256 + threadIdx.x;
  if (e < N_EDGES) atomicAdd(&hist[idx[e]], 1);
}

// 2a) per-block reduce
__global__ __launch_bounds__(256) void k_scan1(const int* __restrict__ hist,
                                               int* __restrict__ blockSum) {
  __shared__ int red[256];
  int t = threadIdx.x;
  int i = blockIdx.x * 256 + t;
  red[t] = (i < N_NODES) ? hist[i] : 0;
  __syncthreads();
  #pragma unroll
  for (int s = 128; s > 0; s >>= 1) {
    if (t < s) red[t] += red[t + s];
    __syncthreads();
  }
  if (t == 0) blockSum[blockIdx.x] = red[0];
}

// 2b) scan of block sums (single block)
__global__ __launch_bounds__(256) void k_scan2(const int* __restrict__ blockSum,
                                               int* __restrict__ blockOff,
                                               int* __restrict__ offs) {
  __shared__ int lds[256];
  int t = threadIdx.x;
  int v = (t < NB_SCAN) ? blockSum[t] : 0;
  lds[t] = v;
  __syncthreads();
  #pragma unroll
  for (int off = 1; off < 256; off <<= 1) {
    int add = (t >= off) ? lds[t - off] : 0;
    __syncthreads();
    lds[t] += add;
    __syncthreads();
  }
  if (t < NB_SCAN) blockOff[t] = lds[t] - v;   // exclusive
  if (t == 255) offs[N_NODES] = lds[255];      // total == N_EDGES
}

// 2c) per-block exclusive scan + offset
__global__ __launch_bounds__(256) void k_scan3(const int* __restrict__ hist,
                                               const int* __restrict__ blockOff,
                                               int* __restrict__ offs,
                                               int* __restrict__ cursor) {
  __shared__ int lds[256];
  int t = threadIdx.x;
  int i = blockIdx.x * 256 + t;
  int v = (i < N_NODES) ? hist[i] : 0;
  lds[t] = v;
  __syncthreads();
  #pragma unroll
  for (int off = 1; off < 256; off <<= 1) {
    int add = (t >= off) ? lds[t - off] : 0;
    __syncthreads();
    lds[t] += add;
    __syncthreads();
  }
  int excl = lds[t] - v + blockOff[blockIdx.x];
  if (i < N_NODES) { offs[i] = excl; cursor[i] = excl; }
}

// 3) scatter edges into CSR buckets as packed (src, w-bits)
__global__ __launch_bounds__(256) void k_scatter(const int* __restrict__ idx,
                                                 const float* __restrict__ w,
                                                 int* __restrict__ cursor,
                                                 int2* __restrict__ edge) {
  int e = blockIdx.x * 256 + threadIdx.x;
  if (e < N_EDGES) {
    int dst = idx[e];
    int p = atomicAdd(&cursor[dst], 1);
    union { float f; int i; } u; u.f = w[e];
    edge[p] = make_int2(idx[N_EDGES + e], u.i);
  }
}

// 4) per-node ordered aggregation: 32 lanes per node, float4 per lane, no atomics
__global__ __launch_bounds__(256) void k_agg(const float* __restrict__ feat,
                                             const int* __restrict__ offs,
                                             const int2* __restrict__ edge,
                                             float* __restrict__ sums) {
  int t = blockIdx.x * 256 + threadIdx.x;
  int node = t >> 5;
  int c = t & 31;
  if (node >= N_NODES) return;
  int beg = offs[node], end = offs[node + 1];
  f32x4 acc = (f32x4){0.f, 0.f, 0.f, 0.f};
  for (int j = beg; j < end; ++j) {
    int2 ed = edge[j];
    union { int i; float f; } u; u.i = ed.y;
    float wt = u.f;
    f32x4 f = *(const f32x4*)(feat + (size_t)ed.x * D + c * 4);
    acc.x += f.x * wt; acc.y += f.y * wt; acc.z += f.z * wt; acc.w += f.w * wt;
  }
  *(f32x4*)(sums + (size_t)node * D + c * 4) = acc;
}

// 5) fused mean + GEMM: out = bf16(feat)@W0 + bf16(sums*invc)@W1 + b.  No LDS.
__global__ __launch_bounds__(256) void k_gemm(const float* __restrict__ feat,
                                              const float* __restrict__ sums,
                                              const int* __restrict__ offs,
                                              const short* __restrict__ wsw,
                                              const float* __restrict__ bias,
                                              float* __restrict__ out) {
  int wave = threadIdx.x >> 6;
  int lane = threadIdx.x & 63;
  int waveId = blockIdx.x * 4 + wave;
  int R = waveId * 16;
  if (R >= N_NODES) return;

  int row_l = lane & 15;
  int kq    = lane >> 4;
  int myrow = R + row_l;

  int deg = offs[myrow + 1] - offs[myrow];
  float invc = 1.0f / fmaxf((float)deg, 1.0f);

  f32x4 acc[8];
  #pragma unroll
  for (int nt = 0; nt < 8; ++nt) acc[nt] = (f32x4){0.f, 0.f, 0.f, 0.f};

  #pragma unroll
  for (int kstep = 0; kstep < 8; ++kstep) {
    int kbase = kstep * 32 + kq * 8;
    const float* srcrow;
    float scale;
    if (kstep < 4) { srcrow = feat + (size_t)myrow * D + kbase;        scale = 1.0f; }
    else           { srcrow = sums + (size_t)myrow * D + (kbase - D);  scale = invc; }
    f32x4 a0 = *(const f32x4*)(srcrow);
    f32x4 a1 = *(const f32x4*)(srcrow + 4);
    bf16x8 af;
    af[0] = f2bf(a0.x * scale); af[1] = f2bf(a0.y * scale);
    af[2] = f2bf(a0.z * scale); af[3] = f2bf(a0.w * scale);
    af[4] = f2bf(a1.x * scale); af[5] = f2bf(a1.y * scale);
    af[6] = f2bf(a1.z * scale); af[7] = f2bf(a1.w * scale);
    const bf16x8* wrow = (const bf16x8*)(wsw + ((size_t)kstep * 8 * 64 + lane) * 8);
    #pragma unroll
    for (int nt = 0; nt < 8; ++nt) {
      bf16x8 bf = wrow[nt * 64];
      acc[nt] = __builtin_amdgcn_mfma_f32_16x16x32_bf16(af, bf, acc[nt], 0, 0, 0);
    }
  }

  // C/D layout: col = lane&15, row = (lane>>4)*4 + reg
  #pragma unroll
  for (int nt = 0; nt < 8; ++nt) {
    int col = nt * 16 + row_l;
    float bv = bias[col];
    #pragma unroll
    for (int r = 0; r < 4; ++r) {
      int orow = R + kq * 4 + r;
      out[(size_t)orow * D + col] = acc[nt][r] + bv;
    }
  }
}

extern "C" void kernel_launch(void* const* d_in, const int* in_sizes, int n_in,
                              void* d_out, int out_size, void* d_ws, size_t ws_size,
                              hipStream_t stream) {
  const float* feature = (const float*)d_in[0];
  const int*   rel_idx = (const int*)d_in[1];
  const float* rel_w   = (const float*)d_in[2];
  const float* W       = (const float*)d_in[3];
  const float* b       = (const float*)d_in[4];
  float* out = (float*)d_out;

  char* ws = (char*)d_ws;
  float* sums  = (float*)(ws + SUMS_OFF);
  short* wsw   = (short*)(ws + WSW_OFF);
  int*   hist  = (int*)(ws + HIST_OFF);
  int*   offs  = (int*)(ws + OFFS_OFF);
  int*   curs  = (int*)(ws + CURS_OFF);
  int2*  edge  = (int2*)(ws + EDGE_OFF);
  int*   bsum  = (int*)(ws + BSUM_OFF);
  int*   boff  = (int*)(ws + BOFF_OFF);

  hipMemsetAsync(hist, 0, N_NODES * sizeof(int), stream);
  k_wswz<<<16, 256, 0, stream>>>(W, wsw);
  k_hist<<<(N_EDGES + 255) / 256, 256, 0, stream>>>(rel_idx, hist);
  k_scan1<<<NB_SCAN, 256, 0, stream>>>(hist, bsum);
  k_scan2<<<1, 256, 0, stream>>>(bsum, boff, offs);
  k_scan3<<<NB_SCAN, 256, 0, stream>>>(hist, boff, offs, curs);
  k_scatter<<<(N_EDGES + 255) / 256, 256, 0, stream>>>(rel_idx, rel_w, curs, edge);
  k_agg<<<(N_NODES * 32 + 255) / 256, 256, 0, stream>>>(feature, offs, edge, sums);
  int gemmBlocks = (N_NODES / 16 + 3) / 4;
  k_gemm<<<gemmBlocks, 256, 0, stream>>>(feature, sums, offs, wsw, b, out);
}